// Round 8
// baseline (476.358 us; speedup 1.0000x reference)
//
#include <hip/hip_runtime.h>

// LSTMNet: SEQ=600, B=4096, IN=6, H=30, OUT=61, fp32 in/out.
// Layout A2-f16-E2: one wave = TWO batch elements sharing one weight set.
//   lane = 32*half + u;  half 0, u<30: gate rows i,f ; half 1: g,o.
// Weights f16x2 (38 VGPRs), consumed by v_dot2_f32_f16 with f32 accum.
// Per step: element 0 full update, element 1 full update, ONE lgkm fence.
// The two elements' chains interleave (ILP); per-step overhead (x loads,
// fence, loop mechanics) amortized 2x vs round 7.
// Last step peeled so the x-prefetch pointer strength-reduces (+= const).

#define SEQ   600
#define BATCH 4096
#define INP   6
#define HID   30
#define NOUT  61

typedef __fp16 f16;
typedef f16  f16x2 __attribute__((ext_vector_type(2)));

__device__ __forceinline__ float rcp_(float x)  { return __builtin_amdgcn_rcpf(x); }
__device__ __forceinline__ float exp2_(float x) { return __builtin_amdgcn_exp2f(x); }
__device__ __forceinline__ f16x2 as_h2(unsigned v) {
    union { unsigned u; f16x2 h; } c; c.u = v; return c.h;
}
#define LOG2E  1.4426950408889634f
#define LOG2E2 2.8853900817779268f

// one element's full LSTM step (dots -> gates -> c,h -> h_sh write)
__device__ __forceinline__ void step_elem(
    const f16x2* __restrict__ wA, const f16x2* __restrict__ wB,
    const f16x2* __restrict__ xwA, const f16x2* __restrict__ xwB,
    float bA, float bB, const uint4* __restrict__ hq,
    f16x2 xh0, f16x2 xh1, f16x2 xh2,
    float mA, float sA, float cA, int half, int lane,
    float& c, f16* __restrict__ hrow)
{
    const uint4 Q0 = hq[0], Q1 = hq[1], Q2 = hq[2], Q3 = hq[3];
    const f16x2 hp[16] = {
        as_h2(Q0.x), as_h2(Q0.y), as_h2(Q0.z), as_h2(Q0.w),
        as_h2(Q1.x), as_h2(Q1.y), as_h2(Q1.z), as_h2(Q1.w),
        as_h2(Q2.x), as_h2(Q2.y), as_h2(Q2.z), as_h2(Q2.w),
        as_h2(Q3.x), as_h2(Q3.y), as_h2(Q3.z), as_h2(Q3.w)
    };

    float aAe = bA, aAo = 0.f, aBe = bB, aBo = 0.f;
    #define DOT(J, E) do {                                            \
        aA##E = __builtin_amdgcn_fdot2(wA[J], hp[J], aA##E, false);   \
        aB##E = __builtin_amdgcn_fdot2(wB[J], hp[J], aB##E, false);   \
    } while (0)
    DOT(0, e);  DOT(1, o);  DOT(2, e);  DOT(3, o);
    DOT(4, e);  DOT(5, o);  DOT(6, e);  DOT(7, o);
    DOT(8, e);  DOT(9, o);  DOT(10, e); DOT(11, o);
    DOT(12, e); DOT(13, o); DOT(14, e);
    #undef DOT
    aAo = __builtin_amdgcn_fdot2(xwA[0], xh0, aAo, false);
    aBo = __builtin_amdgcn_fdot2(xwB[0], xh0, aBo, false);
    aAe = __builtin_amdgcn_fdot2(xwA[1], xh1, aAe, false);
    aBe = __builtin_amdgcn_fdot2(xwB[1], xh1, aBe, false);
    aAo = __builtin_amdgcn_fdot2(xwA[2], xh2, aAo, false);
    aBo = __builtin_amdgcn_fdot2(xwB[2], xh2, aBo, false);

    const float aA = aAe + aAo;
    const float aB = aBe + aBo;

    // half0: nA=sigm_i, nB=sigm_f ; half1: nA=tanh_g, nB=sigm_o
    const float nA = fmaf(sA, rcp_(1.0f + exp2_(mA * aA)), cA);
    const float nB = rcp_(1.0f + exp2_(-LOG2E * aB));

    const float vA = __shfl_xor(nA, 32);
    const float vB = __shfl_xor(nB, 32);

    const float F = half ? vB : nB;   // sigm_f
    const float O = half ? nB : vB;   // sigm_o
    c = fmaf(F, c, nA * vA);          // nA*vA == sigm_i * tanh_g on both halves
    const float tc = 1.0f - 2.0f * rcp_(exp2_(LOG2E2 * c) + 1.0f);
    const float h = O * tc;

    if (lane < HID) hrow[lane] = (f16)h;   // low half writes (RTN)
}

extern "C" __global__ void __launch_bounds__(64, 2)
lstm_fused8(const float* __restrict__ X,   const float* __restrict__ Wih,
            const float* __restrict__ Whh, const float* __restrict__ bih,
            const float* __restrict__ bhh, const float* __restrict__ W1,
            const float* __restrict__ b1,  const float* __restrict__ W2,
            const float* __restrict__ b2,  float* __restrict__ out)
{
    __shared__ __align__(16) f16 h_sh[2][32];   // one h row per element
    __shared__ float o1_sh[2][32];              // fc1 activations

    const int lane = threadIdx.x;          // 0..63 (single-wave block)
    const int u    = lane & 31;
    const int half = lane >> 5;            // 0: gates (i,f); 1: gates (g,o)
    const int uu   = (u < HID) ? u : (HID - 1);
    const int b0   = blockIdx.x * 2;       // two batch elements per wave

    if (lane < 32) { h_sh[0][lane] = (f16)0.f; h_sh[1][lane] = (f16)0.f; }

    // ---- shared weights -> f16x2 registers (one-time RTN casts) ----
    const int rowA = (half ? 2 : 0) * HID + uu;   // i or g
    const int rowB = (half ? 3 : 1) * HID + uu;   // f or o

    const float* ra = Whh + rowA * HID;
    const float* rb = Whh + rowB * HID;
    f16x2 wA[15], wB[15];
    #pragma unroll
    for (int j = 0; j < 15; ++j) {
        wA[j] = f16x2{(f16)ra[2 * j], (f16)ra[2 * j + 1]};
        wB[j] = f16x2{(f16)rb[2 * j], (f16)rb[2 * j + 1]};
    }
    const float* sa = Wih + rowA * INP;
    const float* sb = Wih + rowB * INP;
    f16x2 xwA[3], xwB[3];
    #pragma unroll
    for (int j = 0; j < 3; ++j) {
        xwA[j] = f16x2{(f16)sa[2 * j], (f16)sa[2 * j + 1]};
        xwB[j] = f16x2{(f16)sb[2 * j], (f16)sb[2 * j + 1]};
    }
    float bA = bih[rowA] + bhh[rowA];
    float bB = bih[rowB] + bhh[rowB];
    // (u>=30 lanes hold clamped-row garbage; their outputs are write-guarded)

    #pragma unroll
    for (int j = 0; j < 15; ++j) asm("" : "+v"(wA[j]), "+v"(wB[j]));
    #pragma unroll
    for (int j = 0; j < 3; ++j)  asm("" : "+v"(xwA[j]), "+v"(xwB[j]));
    asm("" : "+v"(bA), "+v"(bB));

    const float mA = half ? -LOG2E2 : -LOG2E;
    const float sA = half ? 2.0f : 1.0f;
    const float cA = half ? -1.0f : 0.0f;

    float c0s = 0.f, c1s = 0.f;

    // x for both elements: 12 contiguous floats = 3 float4 (b0 even -> 48B aligned)
    float4 xq0, xq1, xq2;
    {
        const float4* q = (const float4*)(X + (size_t)b0 * INP);   // t = 0
        xq0 = q[0]; xq1 = q[1]; xq2 = q[2];
    }
    const float* pn = X + (size_t)BATCH * INP + (size_t)b0 * INP;  // t = 1

    asm volatile("s_waitcnt lgkmcnt(0)" ::: "memory");   // h_sh init visible

    const uint4* hq0 = (const uint4*)(&h_sh[0][0]);
    const uint4* hq1 = (const uint4*)(&h_sh[1][0]);

    #define DO_STEP() do {                                                      \
        const f16x2 xa0 = __builtin_amdgcn_cvt_pkrtz(xq0.x, xq0.y);             \
        const f16x2 xa1 = __builtin_amdgcn_cvt_pkrtz(xq0.z, xq0.w);             \
        const f16x2 xa2 = __builtin_amdgcn_cvt_pkrtz(xq1.x, xq1.y);             \
        const f16x2 xb0 = __builtin_amdgcn_cvt_pkrtz(xq1.z, xq1.w);             \
        const f16x2 xb1 = __builtin_amdgcn_cvt_pkrtz(xq2.x, xq2.y);             \
        const f16x2 xb2 = __builtin_amdgcn_cvt_pkrtz(xq2.z, xq2.w);             \
        step_elem(wA, wB, xwA, xwB, bA, bB, hq0, xa0, xa1, xa2,                 \
                  mA, sA, cA, half, lane, c0s, &h_sh[0][0]);                    \
        step_elem(wA, wB, xwA, xwB, bA, bB, hq1, xb0, xb1, xb2,                 \
                  mA, sA, cA, half, lane, c1s, &h_sh[1][0]);                    \
        asm volatile("s_waitcnt lgkmcnt(0)" ::: "memory");                      \
    } while (0)

    for (int t = 0; t < SEQ - 1; ++t) {
        // prefetch x(t+1); pointer strength-reduces (+= 98304 B)
        const float4* q = (const float4*)pn;
        const float4 yq0 = q[0], yq1 = q[1], yq2 = q[2];
        pn += (size_t)BATCH * INP;

        DO_STEP();

        xq0 = yq0; xq1 = yq1; xq2 = yq2;
    }
    DO_STEP();   // t = SEQ-1, no prefetch
    #undef DO_STEP

    // ---- FC1 (lanes 0..29), per element ----
    if (lane < HID) {
        const float* w1r = W1 + lane * HID;
        #pragma unroll
        for (int e = 0; e < 2; ++e) {
            float a1 = b1[lane];
            #pragma unroll
            for (int k = 0; k < HID; ++k) a1 = fmaf(w1r[k], (float)h_sh[e][k], a1);
            o1_sh[e][lane] = a1;
        }
    }
    asm volatile("s_waitcnt lgkmcnt(0)" ::: "memory");

    // ---- FC2 (lanes 0..60), per element ----
    if (lane < NOUT) {
        const float* w2r = W2 + lane * HID;
        #pragma unroll
        for (int e = 0; e < 2; ++e) {
            float a2 = b2[lane];
            #pragma unroll
            for (int k = 0; k < HID; ++k) a2 = fmaf(w2r[k], o1_sh[e][k], a2);
            out[(size_t)(b0 + e) * NOUT + lane] = a2;
        }
    }
}

extern "C" void kernel_launch(void* const* d_in, const int* in_sizes, int n_in,
                              void* d_out, int out_size, void* d_ws, size_t ws_size,
                              hipStream_t stream) {
    const float* X   = (const float*)d_in[0];
    const float* Wih = (const float*)d_in[1];
    const float* Whh = (const float*)d_in[2];
    const float* bih = (const float*)d_in[3];
    const float* bhh = (const float*)d_in[4];
    const float* W1  = (const float*)d_in[5];
    const float* b1  = (const float*)d_in[6];
    const float* W2  = (const float*)d_in[7];
    const float* b2  = (const float*)d_in[8];
    float* out = (float*)d_out;

    dim3 grid(BATCH / 2);   // 2048 single-wave blocks, 2 elements each
    dim3 block(64);
    hipLaunchKernelGGL(lstm_fused8, grid, block, 0, stream,
                       X, Wih, Whh, bih, bhh, W1, b1, W2, b2, out);
}

// Round 9
// 324.495 us; speedup vs baseline: 1.4680x; 1.4680x over previous
//
#include <hip/hip_runtime.h>

// LSTMNet: SEQ=600, B=4096, IN=6, H=30, OUT=61, fp32 in/out.
// Layout A4-f16-E2: one wave = 2 batch elements in PARALLEL halves.
//   lane = 32*half + u; element = blockIdx*2 + half; lane u<30 owns ALL FOUR
//   gate rows (i,f,g,o) of unit u -> c/h update lane-local, NO shuffles.
// Weights stored f16x2 (72 VGPRs), consumed by v_dot2_f32_f16, f32 accum.
// True pressure ~130 fits the 256-reg budget (launch_bounds(64,2)) -> the
// allocator shouldn't demote to AGPR/shuttle (R4's failure at 144 f32 regs).
// h per element in a 32-half LDS row; reads are intra-half broadcasts (free).
// One lgkmcnt fence per step (covers the single ds_write_b16).

#define SEQ   600
#define BATCH 4096
#define INP   6
#define HID   30
#define NOUT  61

typedef __fp16 f16;
typedef f16  f16x2 __attribute__((ext_vector_type(2)));
typedef float f32x2 __attribute__((ext_vector_type(2)));

__device__ __forceinline__ float rcp_(float x)  { return __builtin_amdgcn_rcpf(x); }
__device__ __forceinline__ float exp2_(float x) { return __builtin_amdgcn_exp2f(x); }
__device__ __forceinline__ f16x2 as_h2(unsigned v) {
    union { unsigned u; f16x2 h; } c; c.u = v; return c.h;
}
#define LOG2E  1.4426950408889634f
#define LOG2E2 2.8853900817779268f

extern "C" __global__ void __launch_bounds__(64, 2)
lstm_fused9(const float* __restrict__ X,   const float* __restrict__ Wih,
            const float* __restrict__ Whh, const float* __restrict__ bih,
            const float* __restrict__ bhh, const float* __restrict__ W1,
            const float* __restrict__ b1,  const float* __restrict__ W2,
            const float* __restrict__ b2,  float* __restrict__ out)
{
    __shared__ __align__(16) f16 h_sh[2][32];   // one h row per element
    __shared__ float o1_sh[2][32];              // fc1 activations

    const int lane = threadIdx.x;          // 0..63
    const int half = lane >> 5;            // element slot in wave
    const int u    = lane & 31;            // hidden unit (active u < 30)
    const int uu   = (u < HID) ? u : (HID - 1);   // clamped row for safe loads
    const int b    = blockIdx.x * 2 + half;       // batch element
    const bool act = (u < HID);

    h_sh[half][u] = (f16)0.f;   // 64 lanes cover both 32-entry rows

    // ---- weights -> f16x2 registers, one gate row at a time ----
    // (asm loads block remat; convert per-gate to bound transient f32 regs)
    f16x2 w0[15], w1[15], w2[15], w3[15];   // Whh rows i,f,g,o (15 k-pairs)
    f16x2 x0w[3], x1w[3], x2w[3], x3w[3];   // Wih rows (3 k-pairs)

    #define LOADGATE(Q, WH, XW) do {                                          \
        const float* rr = Whh + (Q * HID + uu) * HID;                         \
        const float* ss = Wih + (Q * HID + uu) * INP;                         \
        f32x2 t[15], tx[3];                                                   \
        _Pragma("unroll")                                                     \
        for (int j = 0; j < 15; ++j)                                          \
            asm volatile("global_load_dwordx2 %0, %1, off"                    \
                         : "=v"(t[j]) : "v"(rr + 2 * j));                     \
        _Pragma("unroll")                                                     \
        for (int j = 0; j < 3; ++j)                                           \
            asm volatile("global_load_dwordx2 %0, %1, off"                    \
                         : "=v"(tx[j]) : "v"(ss + 2 * j));                    \
        asm volatile("s_waitcnt vmcnt(0)" ::: "memory");                      \
        __builtin_amdgcn_sched_barrier(0);  /* keep cvts after the wait */    \
        _Pragma("unroll")                                                     \
        for (int j = 0; j < 15; ++j)                                          \
            WH[j] = __builtin_amdgcn_cvt_pkrtz(t[j].x, t[j].y);               \
        _Pragma("unroll")                                                     \
        for (int j = 0; j < 3; ++j)                                           \
            XW[j] = __builtin_amdgcn_cvt_pkrtz(tx[j].x, tx[j].y);             \
    } while (0)

    LOADGATE(0, w0, x0w);
    LOADGATE(1, w1, x1w);
    LOADGATE(2, w2, x2w);
    LOADGATE(3, w3, x3w);
    #undef LOADGATE

    // pin converted weights so they can't be recomputed/dropped
    #pragma unroll
    for (int j = 0; j < 15; ++j)
        asm("" : "+v"(w0[j]), "+v"(w1[j]), "+v"(w2[j]), "+v"(w3[j]));
    #pragma unroll
    for (int j = 0; j < 3; ++j)
        asm("" : "+v"(x0w[j]), "+v"(x1w[j]), "+v"(x2w[j]), "+v"(x3w[j]));

    float bb0 = 0.f, bb1 = 0.f, bb2 = 0.f, bb3 = 0.f;
    if (act) {
        bb0 = bih[0 * HID + u] + bhh[0 * HID + u];
        bb1 = bih[1 * HID + u] + bhh[1 * HID + u];
        bb2 = bih[2 * HID + u] + bhh[2 * HID + u];
        bb3 = bih[3 * HID + u] + bhh[3 * HID + u];
    }
    asm("" : "+v"(bb0), "+v"(bb1), "+v"(bb2), "+v"(bb3));

    float c = 0.f;

    // x for this lane's element: 6 floats (same addr within a half -> 2 fetches)
    float4 xq; f32x2 xr;
    {
        const float* p = X + (size_t)b * INP;   // t = 0
        xq = *(const float4*)p;
        xr = *(const f32x2*)(p + 4);
    }
    const float* pn = X + (size_t)BATCH * INP + (size_t)b * INP;   // t = 1

    asm volatile("s_waitcnt lgkmcnt(0)" ::: "memory");   // h_sh init visible

    const uint4* hq = (const uint4*)(&h_sh[half][0]);    // 32 halves = 4 x b128

    #define DO_STEP() do {                                                    \
        const f16x2 xh0 = __builtin_amdgcn_cvt_pkrtz(xq.x, xq.y);             \
        const f16x2 xh1 = __builtin_amdgcn_cvt_pkrtz(xq.z, xq.w);             \
        const f16x2 xh2 = __builtin_amdgcn_cvt_pkrtz(xr.x, xr.y);             \
        const uint4 Q0 = hq[0], Q1 = hq[1], Q2 = hq[2], Q3 = hq[3];           \
        const f16x2 hp[16] = {                                                \
            as_h2(Q0.x), as_h2(Q0.y), as_h2(Q0.z), as_h2(Q0.w),               \
            as_h2(Q1.x), as_h2(Q1.y), as_h2(Q1.z), as_h2(Q1.w),               \
            as_h2(Q2.x), as_h2(Q2.y), as_h2(Q2.z), as_h2(Q2.w),               \
            as_h2(Q3.x), as_h2(Q3.y), as_h2(Q3.z), as_h2(Q3.w)               \
        };                                                                    \
        float a0e = bb0, a0o = 0.f, a1e = bb1, a1o = 0.f;                     \
        float a2e = bb2, a2o = 0.f, a3e = bb3, a3o = 0.f;                     \
        _Pragma("unroll")                                                     \
        for (int j = 0; j < 15; j += 2) {                                     \
            a0e = __builtin_amdgcn_fdot2(w0[j], hp[j], a0e, false);           \
            a1e = __builtin_amdgcn_fdot2(w1[j], hp[j], a1e, false);           \
            a2e = __builtin_amdgcn_fdot2(w2[j], hp[j], a2e, false);           \
            a3e = __builtin_amdgcn_fdot2(w3[j], hp[j], a3e, false);           \
            if (j + 1 < 15) {                                                 \
                a0o = __builtin_amdgcn_fdot2(w0[j+1], hp[j+1], a0o, false);   \
                a1o = __builtin_amdgcn_fdot2(w1[j+1], hp[j+1], a1o, false);   \
                a2o = __builtin_amdgcn_fdot2(w2[j+1], hp[j+1], a2o, false);   \
                a3o = __builtin_amdgcn_fdot2(w3[j+1], hp[j+1], a3o, false);   \
            }                                                                 \
        }                                                                     \
        a0o = __builtin_amdgcn_fdot2(x0w[0], xh0, a0o, false);                \
        a1o = __builtin_amdgcn_fdot2(x1w[0], xh0, a1o, false);                \
        a2o = __builtin_amdgcn_fdot2(x2w[0], xh0, a2o, false);                \
        a3o = __builtin_amdgcn_fdot2(x3w[0], xh0, a3o, false);                \
        a0e = __builtin_amdgcn_fdot2(x0w[1], xh1, a0e, false);                \
        a1e = __builtin_amdgcn_fdot2(x1w[1], xh1, a1e, false);                \
        a2e = __builtin_amdgcn_fdot2(x2w[1], xh1, a2e, false);                \
        a3e = __builtin_amdgcn_fdot2(x3w[1], xh1, a3e, false);                \
        a0o = __builtin_amdgcn_fdot2(x0w[2], xh2, a0o, false);                \
        a1o = __builtin_amdgcn_fdot2(x1w[2], xh2, a1o, false);                \
        a2o = __builtin_amdgcn_fdot2(x2w[2], xh2, a2o, false);                \
        a3o = __builtin_amdgcn_fdot2(x3w[2], xh2, a3o, false);                \
        const float g0 = a0e + a0o;   /* i */                                 \
        const float g1 = a1e + a1o;   /* f */                                 \
        const float g2 = a2e + a2o;   /* g */                                 \
        const float g3 = a3e + a3o;   /* o */                                 \
        const float si = rcp_(1.0f + exp2_(-LOG2E * g0));                     \
        const float sf = rcp_(1.0f + exp2_(-LOG2E * g1));                     \
        const float tg = 1.0f - 2.0f * rcp_(exp2_(LOG2E2 * g2) + 1.0f);       \
        const float so = rcp_(1.0f + exp2_(-LOG2E * g3));                     \
        c = fmaf(sf, c, si * tg);                                             \
        const float tc = 1.0f - 2.0f * rcp_(exp2_(LOG2E2 * c) + 1.0f);        \
        const float hv = so * tc;                                             \
        if (act) h_sh[half][u] = (f16)hv;                                     \
        asm volatile("s_waitcnt lgkmcnt(0)" ::: "memory");                    \
    } while (0)

    for (int t = 0; t < SEQ - 1; ++t) {
        // prefetch x(t+1); pointer strength-reduces (+= 98304 B)
        const float4 yq = *(const float4*)pn;
        const f32x2 yr = *(const f32x2*)(pn + 4);
        pn += (size_t)BATCH * INP;

        DO_STEP();

        xq = yq; xr = yr;
    }
    DO_STEP();   // t = SEQ-1, no prefetch
    #undef DO_STEP

    // ---- FC1 (lanes u<30, both halves): o1[u] = b1[u] + sum_k W1[u,k]*h[k] ----
    if (act) {
        float a1 = b1[u];
        const float* w1r = W1 + u * HID;
        #pragma unroll
        for (int k = 0; k < HID; ++k) a1 = fmaf(w1r[k], (float)h_sh[half][k], a1);
        o1_sh[half][u] = a1;
    }
    asm volatile("s_waitcnt lgkmcnt(0)" ::: "memory");

    // ---- FC2: out[b][o] for o = u, u+30 (u=0 also 60) ----
    if (act) {
        for (int o = u; o < NOUT; o += HID) {
            float a2 = b2[o];
            const float* w2r = W2 + o * HID;
            #pragma unroll
            for (int k = 0; k < HID; ++k) a2 = fmaf(w2r[k], o1_sh[half][k], a2);
            out[(size_t)b * NOUT + o] = a2;
        }
    }
}

extern "C" void kernel_launch(void* const* d_in, const int* in_sizes, int n_in,
                              void* d_out, int out_size, void* d_ws, size_t ws_size,
                              hipStream_t stream) {
    const float* X   = (const float*)d_in[0];
    const float* Wih = (const float*)d_in[1];
    const float* Whh = (const float*)d_in[2];
    const float* bih = (const float*)d_in[3];
    const float* bhh = (const float*)d_in[4];
    const float* W1  = (const float*)d_in[5];
    const float* b1  = (const float*)d_in[6];
    const float* W2  = (const float*)d_in[7];
    const float* b2  = (const float*)d_in[8];
    float* out = (float*)d_out;

    dim3 grid(BATCH / 2);   // 2048 single-wave blocks, 2 elements each (halves)
    dim3 block(64);
    hipLaunchKernelGGL(lstm_fused9, grid, block, 0, stream,
                       X, Wih, Whh, bih, bhh, W1, b1, W2, b2, out);
}